// Round 1
// baseline (2370.564 us; speedup 1.0000x reference)
//
#include <hip/hip_runtime.h>
#include <math.h>

// Problem constants
#define NB 64     // batch
#define NN 1024   // tokens per map
#define ND 512    // feature dim
#define NG 8192   // global dim
#define FINF __builtin_inff()

// ---------------- workspace layout (in floats) ----------------
// feat row partials per (b, mtile, n) and col partials per (b, nstrip, m)
static const size_t OFF_FRPV = 0;          // 64*8*1024 = 524288
static const size_t OFF_FRPI = 524288;
static const size_t OFF_FCPV = 1048576;
static const size_t OFF_FCPI = 1572864;
static const size_t OFF_FRV  = 2097152;    // 64*1024 = 65536
static const size_t OFF_FRI  = 2162688;
static const size_t OFF_FCV  = 2228224;
static const size_t OFF_FCI  = 2293760;
static const size_t OFF_LRV  = 2359296;
static const size_t OFF_LRI  = 2424832;
static const size_t OFF_LCV  = 2490368;
static const size_t OFF_LCI  = 2555904;
static const size_t OFF_GP   = 2621440;    // 128*2*4096 = 1048576
static const size_t OFF_SCAL = 3670016;    // 128*8
static const size_t OFF_GS   = 3671040;    // 16
static const size_t OFF_SEL  = 3671056;    // 4*64*10*2 = 5120
// total = 3676176 floats ~= 14.1 MB

__device__ __forceinline__ void upd(float& bv, int& bi, float v, int i){
  // lexicographic (value, index) min: matches jnp.argmin first-occurrence
  // and jax.lax.top_k lower-index-first tie-breaks.
  if (v < bv || (v == bv && i < bi)) { bv = v; bi = i; }
}

// ------------------------------------------------------------------
// K3: batched 128x128 tile of S = A·B^T with fused d2 = ra + rb - 2S
// and row/col (min,argmin) partial outputs. grid = 64 b * 8 nstrip * 8 mtile
// ------------------------------------------------------------------
__global__ __launch_bounds__(256) void feat_tile_kernel(
    const float* __restrict__ A, const float* __restrict__ Bm,
    float* __restrict__ rp_v, int* __restrict__ rp_i,
    float* __restrict__ cp_v, int* __restrict__ cp_i)
{
  const int blk = blockIdx.x;
  const int mt = blk & 7, ns = (blk >> 3) & 7, b = blk >> 6;
  const float* __restrict__ Ab = A  + ((size_t)b*NN + ns*128)*ND;
  const float* __restrict__ Bb = Bm + ((size_t)b*NN + mt*128)*ND;

  // A,B staged transposed [k][row] with pad 132 (132%32==4 -> conflict-light,
  // 132*4B multiple of 16 -> b128-aligned reads)
  __shared__ __align__(16) float As[32*132];
  __shared__ __align__(16) float Bs[32*132];
  __shared__ float rasum[128], rbsum[128];
  __shared__ float colv[16*128];
  __shared__ int   coli[16*128];

  const int t = threadIdx.x;
  const int tx = t & 15, ty = t >> 4;   // 16x16 threads, 8x8 micro-tile

  float acc[8][8];
  #pragma unroll
  for (int i=0;i<8;i++)
    #pragma unroll
    for (int j=0;j<8;j++) acc[i][j]=0.f;
  float ra_acc=0.f, rb_acc=0.f;

  for (int kt=0; kt<ND; kt+=32){
    // stage 128x32 of A and B (float4 coalesced), transposed into LDS
    #pragma unroll
    for (int i=0;i<4;i++){
      int q = t + i*256;              // 0..1023
      int r = q >> 3, f4 = q & 7;
      const float4 av  = *(const float4*)(Ab + (size_t)r*ND + kt + f4*4);
      const float4 bv4 = *(const float4*)(Bb + (size_t)r*ND + kt + f4*4);
      int kk = f4*4;
      As[(kk+0)*132+r]=av.x;  As[(kk+1)*132+r]=av.y;  As[(kk+2)*132+r]=av.z;  As[(kk+3)*132+r]=av.w;
      Bs[(kk+0)*132+r]=bv4.x; Bs[(kk+1)*132+r]=bv4.y; Bs[(kk+2)*132+r]=bv4.z; Bs[(kk+3)*132+r]=bv4.w;
    }
    __syncthreads();

    // squared norms accumulated from LDS (no extra HBM traffic)
    if (t < 128){
      #pragma unroll
      for (int kk=0;kk<32;kk++){ float v=As[kk*132+t]; ra_acc = fmaf(v,v,ra_acc); }
    } else {
      int c = t-128;
      #pragma unroll
      for (int kk=0;kk<32;kk++){ float v=Bs[kk*132+c]; rb_acc = fmaf(v,v,rb_acc); }
    }

    #pragma unroll
    for (int kk=0;kk<32;kk++){
      float a0[8], b0[8];
      *(float4*)&a0[0] = *(const float4*)&As[kk*132 + ty*8];
      *(float4*)&a0[4] = *(const float4*)&As[kk*132 + ty*8 + 4];
      *(float4*)&b0[0] = *(const float4*)&Bs[kk*132 + tx*8];
      *(float4*)&b0[4] = *(const float4*)&Bs[kk*132 + tx*8 + 4];
      #pragma unroll
      for (int i=0;i<8;i++)
        #pragma unroll
        for (int j=0;j<8;j++)
          acc[i][j] = fmaf(a0[i], b0[j], acc[i][j]);
    }
    __syncthreads();
  }

  if (t<128) rasum[t]=ra_acc; else rbsum[t-128]=rb_acc;
  __syncthreads();

  float ra[8], rb[8];
  #pragma unroll
  for (int i=0;i<8;i++){ ra[i]=rasum[ty*8+i]; rb[i]=rbsum[tx*8+i]; }

  const int n0g = ns*128, m0g = mt*128;

  // ---- row partial (min over this 128-col slice) ----
  #pragma unroll
  for (int i=0;i<8;i++){
    float bv = FINF; int bi = 0;
    #pragma unroll
    for (int j=0;j<8;j++){
      float d2 = ra[i] + rb[j] - 2.f*acc[i][j];
      upd(bv, bi, d2, m0g + tx*8 + j);
    }
    #pragma unroll
    for (int off=1; off<16; off<<=1){      // reduce across tx (same wave)
      float ov = __shfl_xor(bv, off);
      int   oi = __shfl_xor(bi, off);
      upd(bv, bi, ov, oi);
    }
    if (tx==0){
      size_t o = ((size_t)b*8 + mt)*NN + n0g + ty*8 + i;
      rp_v[o] = bv; rp_i[o] = bi;
    }
  }

  // ---- col partial (min over this 128-row strip) ----
  #pragma unroll
  for (int j=0;j<8;j++){
    float bv = FINF; int bi = 0;
    #pragma unroll
    for (int i=0;i<8;i++){
      float d2 = ra[i] + rb[j] - 2.f*acc[i][j];
      upd(bv, bi, d2, n0g + ty*8 + i);
    }
    colv[ty*128 + tx*8 + j] = bv;
    coli[ty*128 + tx*8 + j] = bi;
  }
  __syncthreads();
  if (t < 128){
    float bv = FINF; int bi = 0;
    for (int y2=0;y2<16;y2++) upd(bv, bi, colv[y2*128+t], coli[y2*128+t]);
    size_t o = ((size_t)b*8 + ns)*NN + m0g + t;
    cp_v[o]=bv; cp_i[o]=bi;
  }
}

// ------------------------------------------------------------------
// K4: merge 8 partials (ascending tile order preserves first-min ties)
// ------------------------------------------------------------------
__global__ __launch_bounds__(256) void merge_kernel(
    const float* __restrict__ rp_v, const int* __restrict__ rp_i,
    const float* __restrict__ cp_v, const int* __restrict__ cp_i,
    float* __restrict__ row_v, int* __restrict__ row_i,
    float* __restrict__ col_v, int* __restrict__ col_i)
{
  int tid = blockIdx.x*256 + threadIdx.x;   // 0..131071
  int which = tid >> 16;
  int r = tid & 65535;
  int b = r >> 10, n = r & 1023;
  float bv = FINF; int bi = 0;
  if (which == 0){
    #pragma unroll
    for (int p=0;p<8;p++){
      size_t o = ((size_t)b*8+p)*NN + n;
      upd(bv,bi, rp_v[o], rp_i[o]);
    }
    row_v[(size_t)b*NN+n]=bv; row_i[(size_t)b*NN+n]=bi;
  } else {
    #pragma unroll
    for (int p=0;p<8;p++){
      size_t o = ((size_t)b*8+p)*NN + n;
      upd(bv,bi, cp_v[o], cp_i[o]);
    }
    col_v[(size_t)b*NN+n]=bv; col_i[(size_t)b*NN+n]=bi;
  }
}

// ------------------------------------------------------------------
// K_loc: 2-D location distances, full row/col min-argmin per batch
// ------------------------------------------------------------------
__global__ __launch_bounds__(256) void loc_kernel(
    const float* __restrict__ L1, const float* __restrict__ L2,
    float* __restrict__ lr_v, int* __restrict__ lr_i,
    float* __restrict__ lc_v, int* __restrict__ lc_i)
{
  int b = blockIdx.x, t = threadIdx.x;
  __shared__ float2 p1[NN], p2[NN];
  for (int i=t;i<NN;i+=256){
    p1[i] = ((const float2*)L1)[(size_t)b*NN+i];
    p2[i] = ((const float2*)L2)[(size_t)b*NN+i];
  }
  __syncthreads();
  // rows: per n, min over m (strict < keeps first occurrence)
  for (int rr=0; rr<4; rr++){
    int n = rr*256 + t;
    float2 a = p1[n];
    float bv=FINF; int bi=0;
    for (int m=0;m<NN;m++){
      float dx=a.x-p2[m].x, dy=a.y-p2[m].y;
      float d2 = dx*dx+dy*dy;
      if (d2 < bv){ bv=d2; bi=m; }
    }
    lr_v[(size_t)b*NN+n]=bv; lr_i[(size_t)b*NN+n]=bi;
  }
  // cols: per p (x2 element), min over q (x1 candidates)
  for (int rr=0; rr<4; rr++){
    int p = rr*256 + t;
    float2 a = p2[p];
    float bv=FINF; int bi=0;
    for (int q=0;q<NN;q++){
      float dx=a.x-p1[q].x, dy=a.y-p1[q].y;
      float d2 = dx*dx+dy*dy;
      if (d2 < bv){ bv=d2; bi=q; }
    }
    lc_v[(size_t)b*NN+p]=bv; lc_i[(size_t)b*NN+p]=bi;
  }
}

// ------------------------------------------------------------------
// K1: global loss partials. Gram trick: ||Zc^T Zc||_F^2 == ||Zc Zc^T||_F^2,
// and Zc Zc^T is only 64x64 -> never materialize the 8192x8192 covariance.
// ------------------------------------------------------------------
__global__ __launch_bounds__(256) void glob_part_kernel(
    const float* __restrict__ X, const float* __restrict__ Y,
    float* __restrict__ Gpart, float* __restrict__ scalpart)
{
  int blk = blockIdx.x, t = threadIdx.x;   // 128 blocks x 64 columns
  int d0 = blk*64;
  __shared__ float xt[64*65];   // [n][c], pad 65 -> conflict-free column walks
  __shared__ float yt[64*65];
  __shared__ float red[256];

  float inv_part = 0.f;
  #pragma unroll
  for (int i=0;i<16;i++){
    int q = t + i*256;
    int n = q>>6, c = q&63;
    float xv = X[(size_t)n*NG + d0 + c];
    float yv = Y[(size_t)n*NG + d0 + c];
    xt[n*65+c]=xv; yt[n*65+c]=yv;
    float df = xv-yv; inv_part += df*df;
  }
  __syncthreads();

  float relu_part=0.f, csq2_part=0.f;
  if (t < 128){
    int c = t & 63;
    float* Z = (t<64)? xt : yt;
    float s=0.f;
    for (int n=0;n<64;n++) s += Z[n*65+c];
    float mu = s*(1.f/64.f);
    float sq=0.f;
    for (int n=0;n<64;n++){ float v=Z[n*65+c]-mu; Z[n*65+c]=v; sq = fmaf(v,v,sq); }
    float sd = sqrtf(sq*(1.f/63.f));     // ddof=1 over n=64
    relu_part = fmaxf(0.f, 1.f-sd);
    csq2_part = sq*sq;                   // (diag of Z^T Z)_d^2
  }
  __syncthreads();

  // partial 64x64 Gram accumulation over this block's 64 columns
  int ti=(t>>4)*4, tj=(t&15)*4;
  for (int pass=0; pass<2; pass++){
    const float* Z = pass? yt : xt;
    float g[4][4] = {};
    for (int c=0;c<64;c++){
      float vi[4], vj[4];
      #pragma unroll
      for (int k2=0;k2<4;k2++){ vi[k2]=Z[(ti+k2)*65+c]; vj[k2]=Z[(tj+k2)*65+c]; }
      #pragma unroll
      for (int a2=0;a2<4;a2++)
        #pragma unroll
        for (int b2=0;b2<4;b2++) g[a2][b2] = fmaf(vi[a2], vj[b2], g[a2][b2]);
    }
    float* gp = Gpart + ((size_t)blk*2+pass)*4096;
    #pragma unroll
    for (int a2=0;a2<4;a2++)
      #pragma unroll
      for (int b2=0;b2<4;b2++) gp[(ti+a2)*64 + tj + b2] = g[a2][b2];
  }

  auto bsum = [&](float v)->float{
    red[t]=v; __syncthreads();
    for (int s=128;s;s>>=1){ if (t<s) red[t]+=red[t+s]; __syncthreads(); }
    float r=red[0]; __syncthreads(); return r;
  };
  float inv_s = bsum(inv_part);
  float rx_s  = bsum(t<64 ? relu_part : 0.f);
  float ry_s  = bsum((t>=64 && t<128)? relu_part : 0.f);
  float cx_s  = bsum(t<64 ? csq2_part : 0.f);
  float cy_s  = bsum((t>=64 && t<128)? csq2_part : 0.f);
  if (t==0){
    float* sp = scalpart + blk*8;
    sp[0]=inv_s; sp[1]=rx_s; sp[2]=ry_s; sp[3]=cx_s; sp[4]=cy_s;
  }
}

// K2: reduce global partials -> g_inv, g_var, g_cov, g_loss
__global__ __launch_bounds__(256) void glob_reduce_kernel(
    const float* __restrict__ Gpart, const float* __restrict__ scalpart,
    float* __restrict__ gs)
{
  int t = threadIdx.x;
  __shared__ float red[256];
  float ssx=0.f, ssy=0.f;
  for (int e=t; e<4096; e+=256){
    float sx_=0.f, sy_=0.f;
    for (int blk=0; blk<128; blk++){
      sx_ += Gpart[((size_t)blk*2+0)*4096 + e];
      sy_ += Gpart[((size_t)blk*2+1)*4096 + e];
    }
    ssx = fmaf(sx_,sx_,ssx); ssy = fmaf(sy_,sy_,ssy);
  }
  float inv_p=0,rx=0,ry=0,cx=0,cy=0;
  if (t<128){ const float* sp = scalpart + (size_t)t*8; inv_p=sp[0]; rx=sp[1]; ry=sp[2]; cx=sp[3]; cy=sp[4]; }
  auto bsum = [&](float v)->float{
    red[t]=v; __syncthreads();
    for (int s=128;s;s>>=1){ if (t<s) red[t]+=red[t+s]; __syncthreads(); }
    float r=red[0]; __syncthreads(); return r;
  };
  float ssx_s=bsum(ssx), ssy_s=bsum(ssy), inv_s=bsum(inv_p);
  float rx_s=bsum(rx), ry_s=bsum(ry), cx_s=bsum(cx), cy_s=bsum(cy);
  if (t==0){
    float inv = 25.f * inv_s / (64.f*8192.f);
    float var = 15.f*0.5f*(rx_s*(1.f/8192.f) + ry_s*(1.f/8192.f));
    float covx = (ssx_s - cx_s) / (63.f*63.f*8192.f);
    float covy = (ssy_s - cy_s) / (63.f*63.f*8192.f);
    float cov = 0.5f*(covx+covy);
    gs[0]=inv; gs[1]=var; gs[2]=cov; gs[3]=inv+var+cov;
  }
}

// ------------------------------------------------------------------
// K5: top-10 smallest NN distance per (selection, batch); gather channel-0
// features of (element, its NN candidate). One wave per block.
// sel: 0=feat fwd, 1=feat rev, 2=loc fwd, 3=loc rev
// ------------------------------------------------------------------
__global__ __launch_bounds__(64) void select_kernel(
    const float* __restrict__ x1m, const float* __restrict__ x2m,
    const float* __restrict__ frv, const int* __restrict__ fri,
    const float* __restrict__ fcv, const int* __restrict__ fci,
    const float* __restrict__ lrv, const int* __restrict__ lri,
    const float* __restrict__ lcv, const int* __restrict__ lci,
    float* __restrict__ selout)
{
  int sel = blockIdx.x >> 6, b = blockIdx.x & 63;
  const float* nnv; const int* nni; const float* inm; const float* cnm;
  if      (sel==0){ nnv=frv; nni=fri; inm=x1m; cnm=x2m; }
  else if (sel==1){ nnv=fcv; nni=fci; inm=x2m; cnm=x1m; }
  else if (sel==2){ nnv=lrv; nni=lri; inm=x1m; cnm=x2m; }
  else            { nnv=lcv; nni=lci; inm=x2m; cnm=x1m; }

  int lane = threadIdx.x;
  float v[16];
  #pragma unroll
  for (int j=0;j<16;j++) v[j] = nnv[(size_t)b*NN + j*64 + lane];
  __shared__ int wins[10];
  for (int it=0; it<10; it++){
    float bv = FINF; int bi = 0x7fffffff;
    #pragma unroll
    for (int j=0;j<16;j++) upd(bv, bi, v[j], j*64+lane);
    #pragma unroll
    for (int off=1; off<64; off<<=1){
      float ov = __shfl_xor(bv, off);
      int   oi = __shfl_xor(bi, off);
      upd(bv, bi, ov, oi);
    }
    // mark winner as used (static register indexing only)
    #pragma unroll
    for (int j=0;j<16;j++) if (j*64+lane == bi) v[j] = FINF;
    if (lane==0) wins[it] = bi;
  }
  __syncthreads();
  if (lane < 10){
    int e = wins[lane];
    int c = nni[(size_t)b*NN + e];
    float fi = inm[((size_t)b*NN + e)*ND];   // channel 0 only (faithful)
    float fc = cnm[((size_t)b*NN + c)*ND];
    float2* so = (float2*)selout;
    so[((size_t)sel*64 + b)*10 + lane] = make_float2(fi, fc);
  }
}

// K6: local vicreg losses from the 4 selections + final 13-way output
__global__ __launch_bounds__(64) void final_kernel(
    const float* __restrict__ selout, const float* __restrict__ gs,
    float* __restrict__ out)
{
  int lane = threadIdx.x;     // one lane per batch
  float inv_s[4], var_s[4];
  #pragma unroll
  for (int sel=0; sel<4; sel++){
    const float2* so = (const float2*)selout + ((size_t)sel*64 + lane)*10;
    float x[10], y[10];
    float sx=0.f, sy=0.f, sd2=0.f;
    #pragma unroll
    for (int j=0;j<10;j++){
      float2 p = so[j];
      x[j]=p.x; y[j]=p.y;
      sx+=p.x; sy+=p.y;
      float d=p.x-p.y; sd2 = fmaf(d,d,sd2);
    }
    float mx = sx*0.1f, my = sy*0.1f;
    float vx=0.f, vy=0.f;
    #pragma unroll
    for (int j=0;j<10;j++){
      float dx=x[j]-mx, dy=y[j]-my;
      vx = fmaf(dx,dx,vx); vy = fmaf(dy,dy,vy);
    }
    vx *= (1.f/9.f); vy *= (1.f/9.f);      // ddof=1 over 10 matches
    float rx = fmaxf(0.f, 1.f - sqrtf(vx));
    float ry = fmaxf(0.f, 1.f - sqrtf(vy));
    float a=sd2, b2=rx, c=ry;
    #pragma unroll
    for (int off=32; off; off>>=1){
      a  += __shfl_xor(a, off);
      b2 += __shfl_xor(b2, off);
      c  += __shfl_xor(c, off);
    }
    inv_s[sel] = 25.f * a * (1.f/640.f);
    var_s[sel] = 15.f*0.5f*(b2*(1.f/64.f) + c*(1.f/64.f));
  }
  if (lane==0){
    float g_inv=gs[0], g_var=gs[1], g_cov=gs[2], g_loss=gs[3];
    float feat_inv=0.5f*(inv_s[0]+inv_s[1]);
    float feat_var=0.5f*(var_s[0]+var_s[1]);
    float feat_loss=feat_inv+feat_var;            // local cov is exactly 0 (D=1)
    float loc_inv=0.5f*(inv_s[2]+inv_s[3]);
    float loc_var=0.5f*(var_s[2]+var_s[3]);
    float loc_loss=loc_inv+loc_var;
    float total = 0.75f*g_loss + 0.25f*0.5f*(feat_loss+loc_loss);
    out[0]=total;
    out[1]=g_inv;   out[2]=g_var;   out[3]=g_cov; out[4]=g_loss;
    out[5]=loc_inv; out[6]=loc_var; out[7]=0.f;   out[8]=loc_loss;
    out[9]=feat_inv;out[10]=feat_var;out[11]=0.f; out[12]=feat_loss;
  }
}

extern "C" void kernel_launch(void* const* d_in, const int* in_sizes, int n_in,
                              void* d_out, int out_size, void* d_ws, size_t ws_size,
                              hipStream_t stream)
{
  const float* x1m = (const float*)d_in[0];
  const float* x2m = (const float*)d_in[1];
  const float* x1g = (const float*)d_in[2];
  const float* x2g = (const float*)d_in[3];
  const float* x1l = (const float*)d_in[4];
  const float* x2l = (const float*)d_in[5];
  float* out = (float*)d_out;
  float* w = (float*)d_ws;

  float* frpv = w + OFF_FRPV;  int* frpi = (int*)(w + OFF_FRPI);
  float* fcpv = w + OFF_FCPV;  int* fcpi = (int*)(w + OFF_FCPI);
  float* frv  = w + OFF_FRV;   int* fri  = (int*)(w + OFF_FRI);
  float* fcv  = w + OFF_FCV;   int* fci  = (int*)(w + OFF_FCI);
  float* lrv  = w + OFF_LRV;   int* lri  = (int*)(w + OFF_LRI);
  float* lcv  = w + OFF_LCV;   int* lci  = (int*)(w + OFF_LCI);
  float* gp   = w + OFF_GP;
  float* scal = w + OFF_SCAL;
  float* gsc  = w + OFF_GS;
  float* selw = w + OFF_SEL;

  // global loss (Gram-trick)
  glob_part_kernel<<<dim3(128), dim3(256), 0, stream>>>(x1g, x2g, gp, scal);
  glob_reduce_kernel<<<dim3(1), dim3(256), 0, stream>>>(gp, scal, gsc);

  // feature-space distances: fused matmul + row/col min-argmin partials
  feat_tile_kernel<<<dim3(64*8*8), dim3(256), 0, stream>>>(x1m, x2m, frpv, frpi, fcpv, fcpi);
  merge_kernel<<<dim3(512), dim3(256), 0, stream>>>(frpv, frpi, fcpv, fcpi,
                                                    frv, fri, fcv, fci);

  // location-space distances (cheap, direct)
  loc_kernel<<<dim3(64), dim3(256), 0, stream>>>(x1l, x2l, lrv, lri, lcv, lci);

  // top-10 selections + gather, then final assembly of all 13 outputs
  select_kernel<<<dim3(256), dim3(64), 0, stream>>>(x1m, x2m, frv, fri, fcv, fci,
                                                    lrv, lri, lcv, lci, selw);
  final_kernel<<<dim3(1), dim3(64), 0, stream>>>(selw, gsc, out);
}

// Round 2
// 750.048 us; speedup vs baseline: 3.1606x; 3.1606x over previous
//
#include <hip/hip_runtime.h>
#include <math.h>

// Problem constants
#define NB 64     // batch
#define NN 1024   // tokens per map
#define ND 512    // feature dim
#define NG 8192   // global dim
#define FINF __builtin_inff()

typedef unsigned short u16;
typedef unsigned int   u32;
typedef short  short8 __attribute__((ext_vector_type(8)));
typedef float  f32x4  __attribute__((ext_vector_type(4)));

// ---------------- workspace layout ----------------
// Fast path: [Ahl bf16 hi|lo planes][Bhl][partials block]
// Fallback (small ws): [partials block] only, fp32 feat kernel.
static const size_t OFF_AHL = 0;                 // 33554432 floats (134 MB as bf16 pairs)
static const size_t OFF_BHL = 33554432ull;       // 33554432 floats
static const size_t PBASE_FAST = 67108864ull;

// partial-block relative offsets (floats)
static const size_t OFF_FRPV = 0;          // 64*8*1024
static const size_t OFF_FRPI = 524288;
static const size_t OFF_FCPV = 1048576;
static const size_t OFF_FCPI = 1572864;
static const size_t OFF_FRV  = 2097152;    // 64*1024
static const size_t OFF_FRI  = 2162688;
static const size_t OFF_FCV  = 2228224;
static const size_t OFF_FCI  = 2293760;
static const size_t OFF_LRV  = 2359296;
static const size_t OFF_LRI  = 2424832;
static const size_t OFF_LCV  = 2490368;
static const size_t OFF_LCI  = 2555904;
static const size_t OFF_GP   = 2621440;    // 128*2*4096
static const size_t OFF_SCAL = 3670016;    // 128*8
static const size_t OFF_SEL  = 3671056;    // 4*64*10*2
static const size_t OFF_RA   = 3676176;    // 65536
static const size_t OFF_RB   = 3741712;    // 65536
static const size_t OFF_GRED = 3807248;    // 64
static const size_t PBLOCK_END = 3807312;

__device__ __forceinline__ void upd(float& bv, int& bi, float v, int i){
  // lexicographic (value, index) min: matches jnp.argmin first-occurrence
  // and jax.lax.top_k lower-index-first tie-breaks.
  if (v < bv || (v == bv && i < bi)) { bv = v; bi = i; }
}

__device__ __forceinline__ u16 f2bf(float x){
  u32 u = __float_as_uint(x);
  u32 r = u + 0x7FFFu + ((u >> 16) & 1u);   // RNE
  return (u16)(r >> 16);
}
__device__ __forceinline__ float bf2f(u16 h){ return __uint_as_float(((u32)h) << 16); }

// ------------------------------------------------------------------
// convert: fp32 rows -> bf16 hi plane [k<512] + lo plane [512..1024)
// per row, plus exact fp32 squared row-norm. One wave per row.
// ------------------------------------------------------------------
__global__ __launch_bounds__(256) void convert_kernel(
    const float* __restrict__ X, u16* __restrict__ HL, float* __restrict__ norms)
{
  const int wid = threadIdx.x >> 6, lane = threadIdx.x & 63;
  const size_t row = (size_t)blockIdx.x * 4 + wid;     // 0..65535
  const float* src = X + row * ND + lane * 8;
  float4 v0 = *(const float4*)src;
  float4 v1 = *(const float4*)(src + 4);
  float xs[8] = {v0.x, v0.y, v0.z, v0.w, v1.x, v1.y, v1.z, v1.w};
  short8 hi, lo;
  float nrm = 0.f;
  #pragma unroll
  for (int k = 0; k < 8; k++){
    u16 h = f2bf(xs[k]);
    float hf = bf2f(h);
    u16 l = f2bf(xs[k] - hf);
    hi[k] = (short)h; lo[k] = (short)l;
    nrm = fmaf(xs[k], xs[k], nrm);
  }
  #pragma unroll
  for (int off = 1; off < 64; off <<= 1) nrm += __shfl_xor(nrm, off);
  *(short8*)(HL + row * 1024 + lane * 8)       = hi;
  *(short8*)(HL + row * 1024 + 512 + lane * 8) = lo;
  if (lane == 0) norms[row] = nrm;
}

// ------------------------------------------------------------------
// feat MFMA kernel: S = A'·B'^T via 3-pass split-bf16 (hi·hi + hi·lo + lo·hi),
// K_eff = 1536, 128x128 tile, 4 waves, global_load_lds(16B) with XOR chunk
// swizzle (both-sides involution), fused d2 = ra + rb - 2S row/col argmin.
// ------------------------------------------------------------------
__device__ __forceinline__ int akoff(int s){ int p = s >> 3; return ((p == 2) ? 512 : 0) + (s & 7) * 64; }
__device__ __forceinline__ int bkoff(int s){ int p = s >> 3; return ((p == 1) ? 512 : 0) + (s & 7) * 64; }

__global__ __launch_bounds__(256) void feat_mfma_kernel(
    const u16* __restrict__ Ahl, const u16* __restrict__ Bhl,
    const float* __restrict__ ran, const float* __restrict__ rbn,
    float* __restrict__ rp_v, int* __restrict__ rp_i,
    float* __restrict__ cp_v, int* __restrict__ cp_i)
{
  // XCD-aware swizzle (4096 % 8 == 0 -> simple form is bijective)
  const int blk = blockIdx.x;
  const int wg  = (blk & 7) * 512 + (blk >> 3);
  const int b = wg >> 6, t64 = wg & 63;
  const int ns = t64 >> 3, mt = t64 & 7;

  __shared__ u16 As[128 * 64];
  __shared__ u16 Bs[128 * 64];
  __shared__ float ra_s[128], rb_s[128];
  __shared__ float rowv[2][128]; __shared__ int rowi[2][128];
  __shared__ float colv[2][128]; __shared__ int coli[2][128];

  const int t = threadIdx.x;
  const int lane = t & 63, wid = t >> 6;
  const int wr = wid >> 1, wc = wid & 1;
  const int R0 = wr * 64, C0 = wc * 64;
  const int g4 = lane >> 4, l15 = lane & 15, swz = lane & 7;

  const u16* Agrow = Ahl + ((size_t)b * 1024 + ns * 128) * 1024;
  const u16* Bgrow = Bhl + ((size_t)b * 1024 + mt * 128) * 1024;

  if (t < 128) ra_s[t]       = ran[(size_t)b * 1024 + ns * 128 + t];
  else         rb_s[t - 128] = rbn[(size_t)b * 1024 + mt * 128 + (t - 128)];

  f32x4 acc[4][4];
  #pragma unroll
  for (int i = 0; i < 4; i++)
    #pragma unroll
    for (int j = 0; j < 4; j++){ f32x4 z = {0.f, 0.f, 0.f, 0.f}; acc[i][j] = z; }

  auto stage = [&](const u16* grow, u16* lds, int koff){
    #pragma unroll
    for (int i2 = 0; i2 < 4; i2++){
      int c = i2 * 256 + t;                 // 16B chunk id, lane-linear in LDS
      int row = c >> 3, col16 = c & 7;
      int srcc = col16 ^ (row & 7);         // inverse-swizzled GLOBAL source
      const u16* g = grow + (size_t)row * 1024 + koff + srcc * 8;
      __builtin_amdgcn_global_load_lds(
          (const __attribute__((address_space(1))) void*)g,
          (__attribute__((address_space(3))) void*)(lds + c * 8),
          16, 0, 0);
    }
  };

  stage(Agrow, As, akoff(0));
  stage(Bgrow, Bs, bkoff(0));

  for (int s = 0; s < 24; s++){
    __syncthreads();                        // staged data visible (vmcnt drained)
    #pragma unroll
    for (int kk = 0; kk < 64; kk += 32){
      short8 af[4], bfv[4];
      #pragma unroll
      for (int i2 = 0; i2 < 4; i2++){
        int ac16 = ((kk >> 3) + g4) ^ swz;  // swizzled read chunk
        int ar = R0 + i2 * 16 + l15;
        af[i2]  = *(const short8*)&As[ar * 64 + ac16 * 8];
        int br = C0 + i2 * 16 + l15;
        bfv[i2] = *(const short8*)&Bs[br * 64 + ac16 * 8];
      }
      #pragma unroll
      for (int i2 = 0; i2 < 4; i2++)
        #pragma unroll
        for (int j2 = 0; j2 < 4; j2++)
          acc[i2][j2] = __builtin_amdgcn_mfma_f32_16x16x32_bf16(af[i2], bfv[j2], acc[i2][j2], 0, 0, 0);
    }
    __syncthreads();                        // all waves done reading LDS
    if (s < 23){
      stage(Agrow, As, akoff(s + 1));
      stage(Bgrow, Bs, bkoff(s + 1));
    }
  }

  // ---------------- epilogue: d2 + row/col argmin ----------------
  // C/D layout (m89-verified): col = lane&15, row = (lane>>4)*4 + reg
  #pragma unroll
  for (int i2 = 0; i2 < 4; i2++){
    #pragma unroll
    for (int reg = 0; reg < 4; reg++){
      int rloc = R0 + i2 * 16 + g4 * 4 + reg;
      float rav = ra_s[rloc];
      float bv = FINF; int bi = 0;
      #pragma unroll
      for (int j2 = 0; j2 < 4; j2++){
        float d2 = rav + rb_s[C0 + j2 * 16 + l15] - 2.f * acc[i2][j2][reg];
        upd(bv, bi, d2, mt * 128 + C0 + j2 * 16 + l15);
      }
      #pragma unroll
      for (int off = 1; off < 16; off <<= 1){
        float ov = __shfl_xor(bv, off);
        int   oi = __shfl_xor(bi, off);
        upd(bv, bi, ov, oi);
      }
      if (l15 == 0){ rowv[wc][rloc] = bv; rowi[wc][rloc] = bi; }
    }
  }
  #pragma unroll
  for (int j2 = 0; j2 < 4; j2++){
    int cloc = C0 + j2 * 16 + l15;
    float rbv = rb_s[cloc];
    float bv = FINF; int bi = 0;
    #pragma unroll
    for (int i2 = 0; i2 < 4; i2++)
      #pragma unroll
      for (int reg = 0; reg < 4; reg++){
        float d2 = ra_s[R0 + i2 * 16 + g4 * 4 + reg] + rbv - 2.f * acc[i2][j2][reg];
        upd(bv, bi, d2, ns * 128 + R0 + i2 * 16 + g4 * 4 + reg);
      }
    #pragma unroll
    for (int off = 16; off < 64; off <<= 1){
      float ov = __shfl_xor(bv, off);
      int   oi = __shfl_xor(bi, off);
      upd(bv, bi, ov, oi);
    }
    if (g4 == 0){ colv[wr][cloc] = bv; coli[wr][cloc] = bi; }
  }
  __syncthreads();
  if (t < 128){
    float bv = rowv[0][t]; int bi = rowi[0][t];
    upd(bv, bi, rowv[1][t], rowi[1][t]);
    size_t o = ((size_t)b * 8 + mt) * NN + ns * 128 + t;
    rp_v[o] = bv; rp_i[o] = bi;
  } else {
    int c2 = t - 128;
    float bv = colv[0][c2]; int bi = coli[0][c2];
    upd(bv, bi, colv[1][c2], coli[1][c2]);
    size_t o = ((size_t)b * 8 + ns) * NN + mt * 128 + c2;
    cp_v[o] = bv; cp_i[o] = bi;
  }
}

// ------------------------------------------------------------------
// FALLBACK (small ws): fp32 VALU tile kernel (round-1, passing)
// ------------------------------------------------------------------
__global__ __launch_bounds__(256) void feat_tile_kernel(
    const float* __restrict__ A, const float* __restrict__ Bm,
    float* __restrict__ rp_v, int* __restrict__ rp_i,
    float* __restrict__ cp_v, int* __restrict__ cp_i)
{
  const int blk = blockIdx.x;
  const int mt = blk & 7, ns = (blk >> 3) & 7, b = blk >> 6;
  const float* __restrict__ Ab = A  + ((size_t)b*NN + ns*128)*ND;
  const float* __restrict__ Bb = Bm + ((size_t)b*NN + mt*128)*ND;

  __shared__ __align__(16) float As[32*132];
  __shared__ __align__(16) float Bs[32*132];
  __shared__ float rasum[128], rbsum[128];
  __shared__ float colv[16*128];
  __shared__ int   coli[16*128];

  const int t = threadIdx.x;
  const int tx = t & 15, ty = t >> 4;

  float acc[8][8];
  #pragma unroll
  for (int i=0;i<8;i++)
    #pragma unroll
    for (int j=0;j<8;j++) acc[i][j]=0.f;
  float ra_acc=0.f, rb_acc=0.f;

  for (int kt=0; kt<ND; kt+=32){
    #pragma unroll
    for (int i=0;i<4;i++){
      int q = t + i*256;
      int r = q >> 3, f4 = q & 7;
      const float4 av  = *(const float4*)(Ab + (size_t)r*ND + kt + f4*4);
      const float4 bv4 = *(const float4*)(Bb + (size_t)r*ND + kt + f4*4);
      int kk = f4*4;
      As[(kk+0)*132+r]=av.x;  As[(kk+1)*132+r]=av.y;  As[(kk+2)*132+r]=av.z;  As[(kk+3)*132+r]=av.w;
      Bs[(kk+0)*132+r]=bv4.x; Bs[(kk+1)*132+r]=bv4.y; Bs[(kk+2)*132+r]=bv4.z; Bs[(kk+3)*132+r]=bv4.w;
    }
    __syncthreads();
    if (t < 128){
      #pragma unroll
      for (int kk=0;kk<32;kk++){ float v=As[kk*132+t]; ra_acc = fmaf(v,v,ra_acc); }
    } else {
      int c = t-128;
      #pragma unroll
      for (int kk=0;kk<32;kk++){ float v=Bs[kk*132+c]; rb_acc = fmaf(v,v,rb_acc); }
    }
    #pragma unroll
    for (int kk=0;kk<32;kk++){
      float a0[8], b0[8];
      *(float4*)&a0[0] = *(const float4*)&As[kk*132 + ty*8];
      *(float4*)&a0[4] = *(const float4*)&As[kk*132 + ty*8 + 4];
      *(float4*)&b0[0] = *(const float4*)&Bs[kk*132 + tx*8];
      *(float4*)&b0[4] = *(const float4*)&Bs[kk*132 + tx*8 + 4];
      #pragma unroll
      for (int i=0;i<8;i++)
        #pragma unroll
        for (int j=0;j<8;j++)
          acc[i][j] = fmaf(a0[i], b0[j], acc[i][j]);
    }
    __syncthreads();
  }

  if (t<128) rasum[t]=ra_acc; else rbsum[t-128]=rb_acc;
  __syncthreads();

  float ra[8], rb[8];
  #pragma unroll
  for (int i=0;i<8;i++){ ra[i]=rasum[ty*8+i]; rb[i]=rbsum[tx*8+i]; }

  const int n0g = ns*128, m0g = mt*128;

  #pragma unroll
  for (int i=0;i<8;i++){
    float bv = FINF; int bi = 0;
    #pragma unroll
    for (int j=0;j<8;j++){
      float d2 = ra[i] + rb[j] - 2.f*acc[i][j];
      upd(bv, bi, d2, m0g + tx*8 + j);
    }
    #pragma unroll
    for (int off=1; off<16; off<<=1){
      float ov = __shfl_xor(bv, off);
      int   oi = __shfl_xor(bi, off);
      upd(bv, bi, ov, oi);
    }
    if (tx==0){
      size_t o = ((size_t)b*8 + mt)*NN + n0g + ty*8 + i;
      rp_v[o] = bv; rp_i[o] = bi;
    }
  }
  #pragma unroll
  for (int j=0;j<8;j++){
    float bv = FINF; int bi = 0;
    #pragma unroll
    for (int i=0;i<8;i++){
      float d2 = ra[i] + rb[j] - 2.f*acc[i][j];
      upd(bv, bi, d2, n0g + ty*8 + i);
    }
    colv[ty*128 + tx*8 + j] = bv;
    coli[ty*128 + tx*8 + j] = bi;
  }
  __syncthreads();
  if (t < 128){
    float bv = FINF; int bi = 0;
    for (int y2=0;y2<16;y2++) upd(bv, bi, colv[y2*128+t], coli[y2*128+t]);
    size_t o = ((size_t)b*8 + ns)*NN + m0g + t;
    cp_v[o]=bv; cp_i[o]=bi;
  }
}

// ------------------------------------------------------------------
// merge 8 partials (ascending tile order + lex upd keeps first-min ties)
// ------------------------------------------------------------------
__global__ __launch_bounds__(256) void merge_kernel(
    const float* __restrict__ rp_v, const int* __restrict__ rp_i,
    const float* __restrict__ cp_v, const int* __restrict__ cp_i,
    float* __restrict__ row_v, int* __restrict__ row_i,
    float* __restrict__ col_v, int* __restrict__ col_i)
{
  int tid = blockIdx.x*256 + threadIdx.x;
  int which = tid >> 16;
  int r = tid & 65535;
  int b = r >> 10, n = r & 1023;
  float bv = FINF; int bi = 0;
  if (which == 0){
    #pragma unroll
    for (int p=0;p<8;p++){
      size_t o = ((size_t)b*8+p)*NN + n;
      upd(bv,bi, rp_v[o], rp_i[o]);
    }
    row_v[(size_t)b*NN+n]=bv; row_i[(size_t)b*NN+n]=bi;
  } else {
    #pragma unroll
    for (int p=0;p<8;p++){
      size_t o = ((size_t)b*8+p)*NN + n;
      upd(bv,bi, cp_v[o], cp_i[o]);
    }
    col_v[(size_t)b*NN+n]=bv; col_i[(size_t)b*NN+n]=bi;
  }
}

// ------------------------------------------------------------------
// location distances: 4 blocks per batch, 1 row + 1 col per thread
// ------------------------------------------------------------------
__global__ __launch_bounds__(256) void loc_kernel(
    const float* __restrict__ L1, const float* __restrict__ L2,
    float* __restrict__ lr_v, int* __restrict__ lr_i,
    float* __restrict__ lc_v, int* __restrict__ lc_i)
{
  int b = blockIdx.x >> 2, part = blockIdx.x & 3, t = threadIdx.x;
  __shared__ float2 p1[NN], p2[NN];
  for (int i=t;i<NN;i+=256){
    p1[i] = ((const float2*)L1)[(size_t)b*NN+i];
    p2[i] = ((const float2*)L2)[(size_t)b*NN+i];
  }
  __syncthreads();
  int n = part*256 + t;
  {
    float2 a = p1[n];
    float bv=FINF; int bi=0;
    for (int m=0;m<NN;m++){
      float dx=a.x-p2[m].x, dy=a.y-p2[m].y;
      float d2 = dx*dx+dy*dy;
      if (d2 < bv){ bv=d2; bi=m; }
    }
    lr_v[(size_t)b*NN+n]=bv; lr_i[(size_t)b*NN+n]=bi;
  }
  {
    float2 a = p2[n];
    float bv=FINF; int bi=0;
    for (int q=0;q<NN;q++){
      float dx=a.x-p1[q].x, dy=a.y-p1[q].y;
      float d2 = dx*dx+dy*dy;
      if (d2 < bv){ bv=d2; bi=q; }
    }
    lc_v[(size_t)b*NN+n]=bv; lc_i[(size_t)b*NN+n]=bi;
  }
}

// ------------------------------------------------------------------
// global loss partials (Gram trick: ||Zc^T Zc||_F^2 == ||Zc Zc^T||_F^2)
// ------------------------------------------------------------------
__global__ __launch_bounds__(256) void glob_part_kernel(
    const float* __restrict__ X, const float* __restrict__ Y,
    float* __restrict__ Gpart, float* __restrict__ scalpart)
{
  int blk = blockIdx.x, t = threadIdx.x;
  int d0 = blk*64;
  __shared__ float xt[64*65];
  __shared__ float yt[64*65];
  __shared__ float red[256];

  float inv_part = 0.f;
  #pragma unroll
  for (int i=0;i<16;i++){
    int q = t + i*256;
    int n = q>>6, c = q&63;
    float xv = X[(size_t)n*NG + d0 + c];
    float yv = Y[(size_t)n*NG + d0 + c];
    xt[n*65+c]=xv; yt[n*65+c]=yv;
    float df = xv-yv; inv_part += df*df;
  }
  __syncthreads();

  float relu_part=0.f, csq2_part=0.f;
  if (t < 128){
    int c = t & 63;
    float* Z = (t<64)? xt : yt;
    float s=0.f;
    for (int n=0;n<64;n++) s += Z[n*65+c];
    float mu = s*(1.f/64.f);
    float sq=0.f;
    for (int n=0;n<64;n++){ float v=Z[n*65+c]-mu; Z[n*65+c]=v; sq = fmaf(v,v,sq); }
    float sd = sqrtf(sq*(1.f/63.f));
    relu_part = fmaxf(0.f, 1.f-sd);
    csq2_part = sq*sq;
  }
  __syncthreads();

  int ti=(t>>4)*4, tj=(t&15)*4;
  for (int pass=0; pass<2; pass++){
    const float* Z = pass? yt : xt;
    float g[4][4] = {};
    for (int c=0;c<64;c++){
      float vi[4], vj[4];
      #pragma unroll
      for (int k2=0;k2<4;k2++){ vi[k2]=Z[(ti+k2)*65+c]; vj[k2]=Z[(tj+k2)*65+c]; }
      #pragma unroll
      for (int a2=0;a2<4;a2++)
        #pragma unroll
        for (int b2=0;b2<4;b2++) g[a2][b2] = fmaf(vi[a2], vj[b2], g[a2][b2]);
    }
    float* gp = Gpart + ((size_t)blk*2+pass)*4096;
    #pragma unroll
    for (int a2=0;a2<4;a2++)
      #pragma unroll
      for (int b2=0;b2<4;b2++) gp[(ti+a2)*64 + tj + b2] = g[a2][b2];
  }

  auto bsum = [&](float v)->float{
    red[t]=v; __syncthreads();
    for (int s=128;s;s>>=1){ if (t<s) red[t]+=red[t+s]; __syncthreads(); }
    float r=red[0]; __syncthreads(); return r;
  };
  float inv_s = bsum(inv_part);
  float rx_s  = bsum(t<64 ? relu_part : 0.f);
  float ry_s  = bsum((t>=64 && t<128)? relu_part : 0.f);
  float cx_s  = bsum(t<64 ? csq2_part : 0.f);
  float cy_s  = bsum((t>=64 && t<128)? csq2_part : 0.f);
  if (t==0){
    float* sp = scalpart + blk*8;
    sp[0]=inv_s; sp[1]=rx_s; sp[2]=ry_s; sp[3]=cx_s; sp[4]=cy_s;
  }
}

// reduce Gram partials -> per-chunk Frobenius partial sums (32 blocks)
__global__ __launch_bounds__(256) void glob_reduce2_kernel(
    const float* __restrict__ Gpart, float* __restrict__ gred)
{
  int g = blockIdx.x, t = threadIdx.x;
  __shared__ float red[256];
  int pass = t >> 7, e = g*128 + (t & 127);
  float s = 0.f;
  for (int blk=0; blk<128; blk++) s += Gpart[((size_t)blk*2 + pass)*4096 + e];
  red[t] = s*s; __syncthreads();
  for (int st=64; st; st>>=1){ if ((t&127) < st) red[t] += red[t+st]; __syncthreads(); }
  if ((t&127)==0) gred[g*2 + pass] = red[t];
}

// ------------------------------------------------------------------
// top-10 + gather channel-0 features
// ------------------------------------------------------------------
__global__ __launch_bounds__(64) void select_kernel(
    const float* __restrict__ x1m, const float* __restrict__ x2m,
    const float* __restrict__ frv, const int* __restrict__ fri,
    const float* __restrict__ fcv, const int* __restrict__ fci,
    const float* __restrict__ lrv, const int* __restrict__ lri,
    const float* __restrict__ lcv, const int* __restrict__ lci,
    float* __restrict__ selout)
{
  int sel = blockIdx.x >> 6, b = blockIdx.x & 63;
  const float* nnv; const int* nni; const float* inm; const float* cnm;
  if      (sel==0){ nnv=frv; nni=fri; inm=x1m; cnm=x2m; }
  else if (sel==1){ nnv=fcv; nni=fci; inm=x2m; cnm=x1m; }
  else if (sel==2){ nnv=lrv; nni=lri; inm=x1m; cnm=x2m; }
  else            { nnv=lcv; nni=lci; inm=x2m; cnm=x1m; }

  int lane = threadIdx.x;
  float v[16];
  #pragma unroll
  for (int j=0;j<16;j++) v[j] = nnv[(size_t)b*NN + j*64 + lane];
  __shared__ int wins[10];
  for (int it=0; it<10; it++){
    float bv = FINF; int bi = 0x7fffffff;
    #pragma unroll
    for (int j=0;j<16;j++) upd(bv, bi, v[j], j*64+lane);
    #pragma unroll
    for (int off=1; off<64; off<<=1){
      float ov = __shfl_xor(bv, off);
      int   oi = __shfl_xor(bi, off);
      upd(bv, bi, ov, oi);
    }
    #pragma unroll
    for (int j=0;j<16;j++) if (j*64+lane == bi) v[j] = FINF;
    if (lane==0) wins[it] = bi;
  }
  __syncthreads();
  if (lane < 10){
    int e = wins[lane];
    int c = nni[(size_t)b*NN + e];
    float fi = inm[((size_t)b*NN + e)*ND];
    float fc = cnm[((size_t)b*NN + c)*ND];
    float2* so = (float2*)selout;
    so[((size_t)sel*64 + b)*10 + lane] = make_float2(fi, fc);
  }
}

// final: global terms from gred+scalpart, local losses, 13 outputs
__global__ __launch_bounds__(64) void final_kernel(
    const float* __restrict__ selout, const float* __restrict__ gred,
    const float* __restrict__ scalpart, float* __restrict__ out)
{
  int lane = threadIdx.x;
  float ssx = (lane<32)? gred[lane*2]   : 0.f;
  float ssy = (lane<32)? gred[lane*2+1] : 0.f;
  const float* sp0 = scalpart + (size_t)lane*8;
  const float* sp1 = scalpart + (size_t)(lane+64)*8;
  float inv_p = sp0[0]+sp1[0];
  float rx = sp0[1]+sp1[1], ry = sp0[2]+sp1[2];
  float cx = sp0[3]+sp1[3], cy = sp0[4]+sp1[4];
  #pragma unroll
  for (int off=1; off<64; off<<=1){
    ssx += __shfl_xor(ssx,off); ssy += __shfl_xor(ssy,off);
    inv_p += __shfl_xor(inv_p,off);
    rx += __shfl_xor(rx,off); ry += __shfl_xor(ry,off);
    cx += __shfl_xor(cx,off); cy += __shfl_xor(cy,off);
  }

  float inv_s[4], var_s[4];
  #pragma unroll
  for (int sel=0; sel<4; sel++){
    const float2* so = (const float2*)selout + ((size_t)sel*64 + lane)*10;
    float x[10], y[10];
    float sx=0.f, sy=0.f, sd2=0.f;
    #pragma unroll
    for (int j=0;j<10;j++){
      float2 p = so[j];
      x[j]=p.x; y[j]=p.y;
      sx+=p.x; sy+=p.y;
      float d=p.x-p.y; sd2 = fmaf(d,d,sd2);
    }
    float mx = sx*0.1f, my = sy*0.1f;
    float vx=0.f, vy=0.f;
    #pragma unroll
    for (int j=0;j<10;j++){
      float dx=x[j]-mx, dy=y[j]-my;
      vx = fmaf(dx,dx,vx); vy = fmaf(dy,dy,vy);
    }
    vx *= (1.f/9.f); vy *= (1.f/9.f);
    float rvx = fmaxf(0.f, 1.f - sqrtf(vx));
    float rvy = fmaxf(0.f, 1.f - sqrtf(vy));
    float a=sd2, b2=rvx, c=rvy;
    #pragma unroll
    for (int off=32; off; off>>=1){
      a  += __shfl_xor(a, off);
      b2 += __shfl_xor(b2, off);
      c  += __shfl_xor(c, off);
    }
    inv_s[sel] = 25.f * a * (1.f/640.f);
    var_s[sel] = 15.f*0.5f*(b2*(1.f/64.f) + c*(1.f/64.f));
  }
  if (lane==0){
    float g_inv = 25.f * inv_p / (64.f*8192.f);
    float g_var = 15.f*0.5f*((rx+ry)*(1.f/8192.f));
    float covx = (ssx - cx)/(63.f*63.f*8192.f);
    float covy = (ssy - cy)/(63.f*63.f*8192.f);
    float g_cov = 0.5f*(covx+covy);
    float g_loss = g_inv+g_var+g_cov;
    float feat_inv=0.5f*(inv_s[0]+inv_s[1]);
    float feat_var=0.5f*(var_s[0]+var_s[1]);
    float feat_loss=feat_inv+feat_var;
    float loc_inv=0.5f*(inv_s[2]+inv_s[3]);
    float loc_var=0.5f*(var_s[2]+var_s[3]);
    float loc_loss=loc_inv+loc_var;
    float total = 0.75f*g_loss + 0.25f*0.5f*(feat_loss+loc_loss);
    out[0]=total;
    out[1]=g_inv;   out[2]=g_var;   out[3]=g_cov; out[4]=g_loss;
    out[5]=loc_inv; out[6]=loc_var; out[7]=0.f;   out[8]=loc_loss;
    out[9]=feat_inv;out[10]=feat_var;out[11]=0.f; out[12]=feat_loss;
  }
}

extern "C" void kernel_launch(void* const* d_in, const int* in_sizes, int n_in,
                              void* d_out, int out_size, void* d_ws, size_t ws_size,
                              hipStream_t stream)
{
  const float* x1m = (const float*)d_in[0];
  const float* x2m = (const float*)d_in[1];
  const float* x1g = (const float*)d_in[2];
  const float* x2g = (const float*)d_in[3];
  const float* x1l = (const float*)d_in[4];
  const float* x2l = (const float*)d_in[5];
  float* out = (float*)d_out;
  float* w = (float*)d_ws;

  const size_t need_fast = (PBASE_FAST + PBLOCK_END) * 4ull;
  const bool fast = (ws_size >= need_fast);
  const size_t pb = fast ? PBASE_FAST : 0;

  u16* Ahl = (u16*)(w + OFF_AHL);
  u16* Bhl = (u16*)(w + OFF_BHL);
  float* frpv = w + pb + OFF_FRPV;  int* frpi = (int*)(w + pb + OFF_FRPI);
  float* fcpv = w + pb + OFF_FCPV;  int* fcpi = (int*)(w + pb + OFF_FCPI);
  float* frv  = w + pb + OFF_FRV;   int* fri  = (int*)(w + pb + OFF_FRI);
  float* fcv  = w + pb + OFF_FCV;   int* fci  = (int*)(w + pb + OFF_FCI);
  float* lrv  = w + pb + OFF_LRV;   int* lri  = (int*)(w + pb + OFF_LRI);
  float* lcv  = w + pb + OFF_LCV;   int* lci  = (int*)(w + pb + OFF_LCI);
  float* gp   = w + pb + OFF_GP;
  float* scal = w + pb + OFF_SCAL;
  float* selw = w + pb + OFF_SEL;
  float* ra   = w + pb + OFF_RA;
  float* rb   = w + pb + OFF_RB;
  float* gred = w + pb + OFF_GRED;

  if (fast){
    convert_kernel<<<dim3(16384), dim3(256), 0, stream>>>(x1m, Ahl, ra);
    convert_kernel<<<dim3(16384), dim3(256), 0, stream>>>(x2m, Bhl, rb);
    feat_mfma_kernel<<<dim3(4096), dim3(256), 0, stream>>>(Ahl, Bhl, ra, rb,
                                                           frpv, frpi, fcpv, fcpi);
  } else {
    feat_tile_kernel<<<dim3(4096), dim3(256), 0, stream>>>(x1m, x2m, frpv, frpi, fcpv, fcpi);
  }

  merge_kernel<<<dim3(512), dim3(256), 0, stream>>>(frpv, frpi, fcpv, fcpi,
                                                    frv, fri, fcv, fci);

  glob_part_kernel<<<dim3(128), dim3(256), 0, stream>>>(x1g, x2g, gp, scal);
  glob_reduce2_kernel<<<dim3(32), dim3(256), 0, stream>>>(gp, gred);

  loc_kernel<<<dim3(256), dim3(256), 0, stream>>>(x1l, x2l, lrv, lri, lcv, lci);

  select_kernel<<<dim3(256), dim3(64), 0, stream>>>(x1m, x2m, frv, fri, fcv, fci,
                                                    lrv, lri, lcv, lci, selw);
  final_kernel<<<dim3(1), dim3(64), 0, stream>>>(selw, gred, scal, out);
}